// Round 4
// baseline (64.036 us; speedup 1.0000x reference)
//
#include <hip/hip_runtime.h>
#include <hip/hip_bf16.h>

// Problem: B=4, LQ=LK=1024, NHEADS=16, DK=64, D_MODEL=1024.
// out[b,i,d] = 0.125 * sum_{n,k} q[b,i,n,k] * T[b,n,k,d] + fc_b[d]
// T[b,n,k,d] = sum_j k[b,j,n,k] * fc_w[d, j*16+n]
// Factored: stage1 T2t[b][d][n*64+k] = Wt[n] @ Kt[n]^T (16 batches, 1024x256x1024)
//           stage2 out[b] = 0.125 * Qb[b] @ T2t[b]^T + bias (4 batches, 1024^3)

typedef unsigned short u16;
typedef unsigned int u32;
typedef __bf16 bf16x8 __attribute__((ext_vector_type(8)));
typedef float f32x4 __attribute__((ext_vector_type(4)));

__device__ __forceinline__ u16 f2bf(float f) {
  union { float f; unsigned u; } in;
  in.f = f;
  unsigned u = in.u;
  u += 0x7fffu + ((u >> 16) & 1u);  // RNE
  return (u16)(u >> 16);
}

// ---------------- prep_qk: q->bf16 copy + k transpose ----------------
// blocks [0,1024): Qb = bf16(q) identity. blocks [1024,2048): Kt transpose.
__global__ __launch_bounds__(256) void prep_qk(const float* __restrict__ q,
                                               const float* __restrict__ k,
                                               u16* __restrict__ Qb,
                                               u16* __restrict__ Kt) {
  __shared__ u16 lds[64][65];
  const int tid = threadIdx.x;
  const int bid = blockIdx.x;

  if (bid < 1024) {
    // role q: pure streaming copy+convert, 4 float4 in flight.
    int idx = bid * 256 + tid;
    float4 r[4];
#pragma unroll
    for (int it = 0; it < 4; ++it)
      r[it] = reinterpret_cast<const float4*>(q)[it * 262144 + idx];
#pragma unroll
    for (int it = 0; it < 4; ++it) {
      ushort4 o;
      o.x = f2bf(r[it].x); o.y = f2bf(r[it].y);
      o.z = f2bf(r[it].z); o.w = f2bf(r[it].w);
      reinterpret_cast<ushort4*>(Qb)[it * 262144 + idx] = o;
    }
  } else {
    // role k: Kt[n][b*64+kk][j] = k[b][j][n][kk]
    int e = bid - 1024;
    int jt = e & 15, n = (e >> 4) & 15, b = e >> 8;
    const int j0 = jt * 64;
    float4 r[4];
#pragma unroll
    for (int it = 0; it < 4; ++it) {
      int idx = it * 256 + tid;
      int jj = idx >> 4;
      int c4 = idx & 15;
      r[it] = *reinterpret_cast<const float4*>(
          &k[(((size_t)b * 1024 + j0 + jj) * 16 + n) * 64 + c4 * 4]);
    }
#pragma unroll
    for (int it = 0; it < 4; ++it) {
      int idx = it * 256 + tid;
      int jj = idx >> 4;
      int c4 = idx & 15;
      lds[c4 * 4 + 0][jj] = f2bf(r[it].x);
      lds[c4 * 4 + 1][jj] = f2bf(r[it].y);
      lds[c4 * 4 + 2][jj] = f2bf(r[it].z);
      lds[c4 * 4 + 3][jj] = f2bf(r[it].w);
    }
    __syncthreads();
    ushort4 o[4];
#pragma unroll
    for (int it = 0; it < 4; ++it) {
      int idx = it * 256 + tid;
      int kk = idx >> 4;
      int c4 = idx & 15;
      o[it].x = lds[kk][c4 * 4 + 0]; o[it].y = lds[kk][c4 * 4 + 1];
      o[it].z = lds[kk][c4 * 4 + 2]; o[it].w = lds[kk][c4 * 4 + 3];
    }
#pragma unroll
    for (int it = 0; it < 4; ++it) {
      int idx = it * 256 + tid;
      int kk = idx >> 4;
      int c4 = idx & 15;
      *reinterpret_cast<ushort4*>(
          &Kt[((size_t)n * 256 + b * 64 + kk) * 1024 + j0 + c4 * 4]) = o[it];
    }
  }
}

// ---------------- prep_w: Wt[n][d][j] = fc_w[d][j*16+n] ----------------
// block = (d, h): d = bid>>1 in [0,1024), h = bid&1 half-slab of 512 j.
// Reads 32KB coalesced (paired-offset mapping puts j and j+1 in one lane),
// LDS de-interleave with packed b32 writes (0 bank conflicts:
// word addr = n*260 + a, 260%32=4, n0*{0..3} x a spans all 32 banks),
// write-out 512B-contiguous wave stores.
__global__ __launch_bounds__(256) void prep_w(const float* __restrict__ w,
                                              u16* __restrict__ Wt) {
  __shared__ u16 lds[16 * 520];  // [n][520], 16.6 KB
  u32* lds32 = reinterpret_cast<u32*>(lds);
  const int tid = threadIdx.x;
  const int d = blockIdx.x >> 1;
  const int h = blockIdx.x & 1;
  const float* src = w + (size_t)d * 16384 + h * 8192;

  // load 8 float4 (4 pairs): g1 = it*512 + (tid>>2)*8 + (tid&3), g2 = g1+4
  float4 ra[4], rb[4];
  const int gbase = ((tid >> 2) << 3) + (tid & 3);
#pragma unroll
  for (int it = 0; it < 4; ++it) {
    int g1 = it * 512 + gbase;
    ra[it] = reinterpret_cast<const float4*>(src)[g1];
    rb[it] = reinterpret_cast<const float4*>(src)[g1 + 4];
  }
  // de-interleave: g = 4a + (tid&3); element e -> n = (tid&3)*4+e, col a (and a+1)
  const int n0 = (tid & 3) * 4;
#pragma unroll
  for (int it = 0; it < 4; ++it) {
    int a = (it * 512 + gbase) >> 2;  // even
#pragma unroll
    for (int e = 0; e < 4; ++e) {
      float lo = (&ra[it].x)[e], hi = (&rb[it].x)[e];
      lds32[(n0 + e) * 260 + (a >> 1)] = (u32)f2bf(lo) | ((u32)f2bf(hi) << 16);
    }
  }
  __syncthreads();
  // write-out: wave = rows 4w..4w+3, 8 segs of 512B contiguous
  const int wv = tid >> 6, lane = tid & 63;
  ushort4 o[8];
#pragma unroll
  for (int s = 0; s < 8; ++s) {
    int row = 4 * wv + (s >> 1);
    int col = (s & 1) * 256 + lane * 4;
    o[s] = *reinterpret_cast<const ushort4*>(&lds[row * 520 + col]);
  }
#pragma unroll
  for (int s = 0; s < 8; ++s) {
    int row = 4 * wv + (s >> 1);
    int col = (s & 1) * 256 + lane * 4;
    *reinterpret_cast<ushort4*>(
        &Wt[(size_t)row * 1048576 + (size_t)d * 1024 + h * 512 + col]) = o[s];
  }
}

// ---------------- pipelined GEMM: C = A @ B^T, K=1024, tile 128x128, BK=64 ----------------
// 4 LDS buffers (128 KB), depth-3 prefetch, 1 barrier per K-step, counted vmcnt.
// XOR-swizzled LDS (both sides: pre-swizzled gload_lds source + swizzled ds_read).
template <int VM>
__device__ __forceinline__ void waitVm() {
  if constexpr (VM == 16) asm volatile("s_waitcnt vmcnt(16)" ::: "memory");
  else if constexpr (VM == 8) asm volatile("s_waitcnt vmcnt(8)" ::: "memory");
  else asm volatile("s_waitcnt vmcnt(0)" ::: "memory");
}

template <int TN_TILES, int STAGE>
__global__ __launch_bounds__(256, 1) void gemm_bt(const u16* __restrict__ Abase,
                                                  const u16* __restrict__ Bbase,
                                                  u16* __restrict__ CoutBf,
                                                  float* __restrict__ CoutF,
                                                  const float* __restrict__ bias) {
  __shared__ u16 AB[4][2][128 * 64];  // [buf][A/B][row*64+col], 128 KB
  const int tid = threadIdx.x;
  const int wid = tid >> 6;
  const int lane = tid & 63;
  const int batch = blockIdx.y;
  const int tm = blockIdx.x / TN_TILES;
  const int tn = blockIdx.x % TN_TILES;

  const u16* A = Abase + (size_t)batch * 1048576;
  const u16* B = Bbase + (size_t)batch * ((STAGE == 1) ? 262144 : 1048576);
  const int row0A = tm * 128, row0B = tn * 128;

  const int wr = wid >> 1;
  const int wc = wid & 1;
  const int laneRow = lane & 15;
  const int hi8 = (lane >> 4) * 8;
  const int swz = (lane & 7) * 8;

  f32x4 acc[4][4] = {};

  auto stage = [&](int tIdx) {
    const int kt = tIdx * 64;
    u16* lA = &AB[tIdx & 3][0][0];
    u16* lB = &AB[tIdx & 3][1][0];
#pragma unroll
    for (int i = 0; i < 4; ++i) {
      int p = i * 256 + tid;                  // 16B chunk id, 0..1023
      int r = p >> 3;                         // row 0..127
      int sc = ((p & 7) ^ (r & 7)) * 8;       // swizzled source col (elems)
      const u16* gA = A + (size_t)(row0A + r) * 1024 + kt + sc;
      const u16* gB = B + (size_t)(row0B + r) * 1024 + kt + sc;
      __builtin_amdgcn_global_load_lds(
          (const __attribute__((address_space(1))) void*)gA,
          (__attribute__((address_space(3))) void*)(lA + i * 2048 + wid * 512), 16, 0, 0);
      __builtin_amdgcn_global_load_lds(
          (const __attribute__((address_space(1))) void*)gB,
          (__attribute__((address_space(3))) void*)(lB + i * 2048 + wid * 512), 16, 0, 0);
    }
  };

  auto compute = [&](int tIdx) {
    const u16* At = &AB[tIdx & 3][0][0];
    const u16* Bt = &AB[tIdx & 3][1][0];
    bf16x8 af[2][4], bq[2][4];
#pragma unroll
    for (int kh = 0; kh < 2; ++kh) {
      int cs = (kh * 32 + hi8) ^ swz;  // swizzled read col
#pragma unroll
      for (int mi = 0; mi < 4; ++mi)
        af[kh][mi] = *reinterpret_cast<const bf16x8*>(
            &At[(wr * 64 + mi * 16 + laneRow) * 64 + cs]);
#pragma unroll
      for (int ni = 0; ni < 4; ++ni)
        bq[kh][ni] = *reinterpret_cast<const bf16x8*>(
            &Bt[(wc * 64 + ni * 16 + laneRow) * 64 + cs]);
    }
#pragma unroll
    for (int kh = 0; kh < 2; ++kh)
#pragma unroll
      for (int mi = 0; mi < 4; ++mi)
#pragma unroll
        for (int ni = 0; ni < 4; ++ni)
          acc[mi][ni] = __builtin_amdgcn_mfma_f32_16x16x32_bf16(
              af[kh][mi], bq[kh][ni], acc[mi][ni], 0, 0, 0);
  };

  // prologue: 3 tiles in flight (24 loads/thread outstanding)
  stage(0); stage(1); stage(2);

  for (int t = 0; t < 13; ++t) {
    waitVm<16>();
    __builtin_amdgcn_s_barrier();
    stage(t + 3);
    compute(t);
  }
  waitVm<16>(); __builtin_amdgcn_s_barrier(); compute(13);
  waitVm<8>();  __builtin_amdgcn_s_barrier(); compute(14);
  waitVm<0>();  __builtin_amdgcn_s_barrier(); compute(15);

  // epilogue: D frag layout col=lane&15, row=(lane>>4)*4+q
#pragma unroll
  for (int mi = 0; mi < 4; ++mi) {
#pragma unroll
    for (int ni = 0; ni < 4; ++ni) {
      int colg = tn * 128 + wc * 64 + ni * 16 + laneRow;
#pragma unroll
      for (int qq = 0; qq < 4; ++qq) {
        int rowg = tm * 128 + wr * 64 + mi * 16 + (lane >> 4) * 4 + qq;
        if (STAGE == 1) {
          size_t off = (size_t)(colg >> 6) * 1048576 + (size_t)rowg * 1024 +
                       (size_t)batch * 64 + (colg & 63);
          CoutBf[off] = f2bf(acc[mi][ni][qq]);
        } else {
          CoutF[(size_t)batch * 1048576 + (size_t)rowg * 1024 + colg] =
              acc[mi][ni][qq] * 0.125f + bias[colg];
        }
      }
    }
  }
}

extern "C" void kernel_launch(void* const* d_in, const int* in_sizes, int n_in,
                              void* d_out, int out_size, void* d_ws, size_t ws_size,
                              hipStream_t stream) {
  const float* q    = (const float*)d_in[0];
  const float* k    = (const float*)d_in[1];
  // d_in[2] = v — unused by the reference output
  const float* fc_w = (const float*)d_in[3];
  const float* fc_b = (const float*)d_in[4];
  float* out = (float*)d_out;

  char* ws = (char*)d_ws;
  if (ws_size < 58720256) return;  // need 56 MB scratch
  u16* Qb  = (u16*)(ws);             // [4][1024][1024]   8.4 MB
  u16* Kt  = (u16*)(ws + 8388608);   // [16][256][1024]   8.4 MB
  u16* Wt  = (u16*)(ws + 16777216);  // [16][1024][1024] 33.6 MB
  u16* T2t = (u16*)(ws + 50331648);  // [4][1024][1024]   8.4 MB

  prep_qk<<<2048, 256, 0, stream>>>(q, k, Qb, Kt);
  prep_w<<<2048, 256, 0, stream>>>(fc_w, Wt);
  gemm_bt<2, 1><<<dim3(16, 16), 256, 0, stream>>>(Wt, Kt, T2t, nullptr, nullptr);
  gemm_bt<8, 2><<<dim3(64, 4), 256, 0, stream>>>(Qb, T2t, nullptr, out, fc_b);
}

// Round 5
// 60.572 us; speedup vs baseline: 1.0572x; 1.0572x over previous
//
#include <hip/hip_runtime.h>
#include <hip/hip_bf16.h>

// Problem: B=4, LQ=LK=1024, NHEADS=16, DK=64, D_MODEL=1024.
// out[b,i,d] = 0.125 * sum_{n,k} q[b,i,n,k] * T[b,n,k,d] + fc_b[d]
// T[b,n,k,d] = sum_j k[b,j,n,k] * fc_w[d, j*16+n]
// Factored: stage1 T2t[b][d][n*64+k] = Wt[n] @ Kt[n]^T (16 batches, 1024x256x1024)
//           stage2 out[b] = 0.125 * Qb[b] @ T2t[b]^T + bias (4 batches, 1024^3)
// q->bf16 conversion is folded into gemm1's epilogue (streams while blocks drain).

typedef unsigned short u16;
typedef unsigned int u32;
typedef __bf16 bf16x8 __attribute__((ext_vector_type(8)));
typedef float f32x4 __attribute__((ext_vector_type(4)));
typedef u16 u16x8 __attribute__((ext_vector_type(8)));

__device__ __forceinline__ u16 f2bf(float f) {
  union { float f; unsigned u; } in;
  in.f = f;
  unsigned u = in.u;
  u += 0x7fffu + ((u >> 16) & 1u);  // RNE
  return (u16)(u >> 16);
}

// ---------------- prep: k transpose + fc_w de-interleave (merged roles) ----------------
// blocks [0,1024): Kt[n][b*64+kk][j] = k[b][j][n][kk]
// blocks [1024,3072): Wt[n][d][j] = fc_w[d][j*16+n]  (1 d-row x half-slab per block)
__global__ __launch_bounds__(256) void prep(const float* __restrict__ k,
                                            const float* __restrict__ w,
                                            u16* __restrict__ Kt,
                                            u16* __restrict__ Wt) {
  __shared__ u16 lds[16 * 520];  // 16.6 KB, reused per role
  const int tid = threadIdx.x;
  const int bid = blockIdx.x;

  if (bid < 1024) {
    // role k
    int jt = bid & 15, n = (bid >> 4) & 15, b = bid >> 8;
    auto l2 = reinterpret_cast<u16(*)[65]>(lds);  // [kk][jj], 8320B
    const int j0 = jt * 64;
    float4 r[4];
#pragma unroll
    for (int it = 0; it < 4; ++it) {
      int idx = it * 256 + tid;
      int jj = idx >> 4;
      int c4 = idx & 15;
      r[it] = *reinterpret_cast<const float4*>(
          &k[(((size_t)b * 1024 + j0 + jj) * 16 + n) * 64 + c4 * 4]);
    }
#pragma unroll
    for (int it = 0; it < 4; ++it) {
      int idx = it * 256 + tid;
      int jj = idx >> 4;
      int c4 = idx & 15;
      l2[c4 * 4 + 0][jj] = f2bf(r[it].x);
      l2[c4 * 4 + 1][jj] = f2bf(r[it].y);
      l2[c4 * 4 + 2][jj] = f2bf(r[it].z);
      l2[c4 * 4 + 3][jj] = f2bf(r[it].w);
    }
    __syncthreads();
    ushort4 o[4];
#pragma unroll
    for (int it = 0; it < 4; ++it) {
      int idx = it * 256 + tid;
      int kk = idx >> 4;
      int c4 = idx & 15;
      o[it].x = l2[kk][c4 * 4 + 0]; o[it].y = l2[kk][c4 * 4 + 1];
      o[it].z = l2[kk][c4 * 4 + 2]; o[it].w = l2[kk][c4 * 4 + 3];
    }
#pragma unroll
    for (int it = 0; it < 4; ++it) {
      int idx = it * 256 + tid;
      int kk = idx >> 4;
      int c4 = idx & 15;
      *reinterpret_cast<ushort4*>(
          &Kt[((size_t)n * 256 + b * 64 + kk) * 1024 + j0 + c4 * 4]) = o[it];
    }
  } else {
    // role w: d = e>>1, h = e&1 (half-slab of 512 j)
    int e = bid - 1024;
    const int d = e >> 1;
    const int h = e & 1;
    u32* lds32 = reinterpret_cast<u32*>(lds);
    const float* src = w + (size_t)d * 16384 + h * 8192;

    float4 ra[4], rb[4];
    const int gbase = ((tid >> 2) << 3) + (tid & 3);
#pragma unroll
    for (int it = 0; it < 4; ++it) {
      int g1 = it * 512 + gbase;
      ra[it] = reinterpret_cast<const float4*>(src)[g1];
      rb[it] = reinterpret_cast<const float4*>(src)[g1 + 4];
    }
    const int n0 = (tid & 3) * 4;
#pragma unroll
    for (int it = 0; it < 4; ++it) {
      int a = (it * 512 + gbase) >> 2;  // even
#pragma unroll
      for (int el = 0; el < 4; ++el) {
        float lo = (&ra[it].x)[el], hi = (&rb[it].x)[el];
        lds32[(n0 + el) * 260 + (a >> 1)] = (u32)f2bf(lo) | ((u32)f2bf(hi) << 16);
      }
    }
    __syncthreads();
    // store: wave wv owns n-rows 4wv..4wv+3; 1KB contiguous per row
    const int wv = tid >> 6, lane = tid & 63;
    u16x8 o[4];
#pragma unroll
    for (int s = 0; s < 4; ++s)
      o[s] = *reinterpret_cast<const u16x8*>(&lds[(4 * wv + s) * 520 + lane * 8]);
#pragma unroll
    for (int s = 0; s < 4; ++s) {
      int n = 4 * wv + s;
      *reinterpret_cast<u16x8*>(
          &Wt[(size_t)n * 1048576 + (size_t)d * 1024 + h * 512 + lane * 8]) = o[s];
    }
  }
}

// ---------------- pipelined GEMM: C = A @ B^T, K=1024, tile 128x128, BK=64 ----------------
// 4 LDS buffers (128 KB), depth-3 prefetch, 1 barrier per K-step, counted vmcnt.
// XOR-swizzled LDS (both sides: pre-swizzled gload_lds source + swizzled ds_read).
// STAGE 1 additionally streams a 64KB chunk of q -> Qb bf16 in its epilogue.
template <int VM>
__device__ __forceinline__ void waitVm() {
  if constexpr (VM == 16) asm volatile("s_waitcnt vmcnt(16)" ::: "memory");
  else if constexpr (VM == 8) asm volatile("s_waitcnt vmcnt(8)" ::: "memory");
  else asm volatile("s_waitcnt vmcnt(0)" ::: "memory");
}

template <int TN_TILES, int STAGE>
__global__ __launch_bounds__(256, 1) void gemm_bt(const u16* __restrict__ Abase,
                                                  const u16* __restrict__ Bbase,
                                                  u16* __restrict__ CoutBf,
                                                  float* __restrict__ CoutF,
                                                  const float* __restrict__ bias,
                                                  const float* __restrict__ qsrc,
                                                  u16* __restrict__ qdst) {
  __shared__ u16 AB[4][2][128 * 64];  // [buf][A/B][row*64+col], 128 KB
  const int tid = threadIdx.x;
  const int wid = tid >> 6;
  const int lane = tid & 63;
  const int batch = blockIdx.y;
  const int tm = blockIdx.x / TN_TILES;
  const int tn = blockIdx.x % TN_TILES;

  const u16* A = Abase + (size_t)batch * 1048576;
  const u16* B = Bbase + (size_t)batch * ((STAGE == 1) ? 262144 : 1048576);
  const int row0A = tm * 128, row0B = tn * 128;

  const int wr = wid >> 1;
  const int wc = wid & 1;
  const int laneRow = lane & 15;
  const int hi8 = (lane >> 4) * 8;
  const int swz = (lane & 7) * 8;

  f32x4 acc[4][4] = {};

  auto stage = [&](int tIdx) {
    const int kt = tIdx * 64;
    u16* lA = &AB[tIdx & 3][0][0];
    u16* lB = &AB[tIdx & 3][1][0];
#pragma unroll
    for (int i = 0; i < 4; ++i) {
      int p = i * 256 + tid;                  // 16B chunk id, 0..1023
      int r = p >> 3;                         // row 0..127
      int sc = ((p & 7) ^ (r & 7)) * 8;       // swizzled source col (elems)
      const u16* gA = A + (size_t)(row0A + r) * 1024 + kt + sc;
      const u16* gB = B + (size_t)(row0B + r) * 1024 + kt + sc;
      __builtin_amdgcn_global_load_lds(
          (const __attribute__((address_space(1))) void*)gA,
          (__attribute__((address_space(3))) void*)(lA + i * 2048 + wid * 512), 16, 0, 0);
      __builtin_amdgcn_global_load_lds(
          (const __attribute__((address_space(1))) void*)gB,
          (__attribute__((address_space(3))) void*)(lB + i * 2048 + wid * 512), 16, 0, 0);
    }
  };

  auto compute = [&](int tIdx) {
    const u16* At = &AB[tIdx & 3][0][0];
    const u16* Bt = &AB[tIdx & 3][1][0];
    bf16x8 af[2][4], bq[2][4];
#pragma unroll
    for (int kh = 0; kh < 2; ++kh) {
      int cs = (kh * 32 + hi8) ^ swz;  // swizzled read col
#pragma unroll
      for (int mi = 0; mi < 4; ++mi)
        af[kh][mi] = *reinterpret_cast<const bf16x8*>(
            &At[(wr * 64 + mi * 16 + laneRow) * 64 + cs]);
#pragma unroll
      for (int ni = 0; ni < 4; ++ni)
        bq[kh][ni] = *reinterpret_cast<const bf16x8*>(
            &Bt[(wc * 64 + ni * 16 + laneRow) * 64 + cs]);
    }
#pragma unroll
    for (int kh = 0; kh < 2; ++kh)
#pragma unroll
      for (int mi = 0; mi < 4; ++mi)
#pragma unroll
        for (int ni = 0; ni < 4; ++ni)
          acc[mi][ni] = __builtin_amdgcn_mfma_f32_16x16x32_bf16(
              af[kh][mi], bq[kh][ni], acc[mi][ni], 0, 0, 0);
  };

  // prologue: 3 tiles in flight (24 loads/thread outstanding)
  stage(0); stage(1); stage(2);

  for (int t = 0; t < 13; ++t) {
    waitVm<16>();
    __builtin_amdgcn_s_barrier();
    stage(t + 3);
    compute(t);
  }
  waitVm<16>(); __builtin_amdgcn_s_barrier(); compute(13);
  waitVm<8>();  __builtin_amdgcn_s_barrier(); compute(14);
  waitVm<0>();  __builtin_amdgcn_s_barrier(); compute(15);

  // epilogue: D frag layout col=lane&15, row=(lane>>4)*4+q
#pragma unroll
  for (int mi = 0; mi < 4; ++mi) {
#pragma unroll
    for (int ni = 0; ni < 4; ++ni) {
      int colg = tn * 128 + wc * 64 + ni * 16 + laneRow;
#pragma unroll
      for (int qq = 0; qq < 4; ++qq) {
        int rowg = tm * 128 + wr * 64 + mi * 16 + (lane >> 4) * 4 + qq;
        if (STAGE == 1) {
          size_t off = (size_t)(colg >> 6) * 1048576 + (size_t)rowg * 1024 +
                       (size_t)batch * 64 + (colg & 63);
          CoutBf[off] = f2bf(acc[mi][ni][qq]);
        } else {
          CoutF[(size_t)batch * 1048576 + (size_t)rowg * 1024 + colg] =
              acc[mi][ni][qq] * 0.125f + bias[colg];
        }
      }
    }
  }

  // stage1 tail: stream-convert this block's 64KB chunk of q -> Qb
  if (STAGE == 1) {
    const int cb = batch * 16 + blockIdx.x;  // grid (16,16) -> 256 unique
    const float4* src = reinterpret_cast<const float4*>(qsrc) + (size_t)cb * 4096;
    ushort4* dst = reinterpret_cast<ushort4*>(qdst) + (size_t)cb * 4096;
#pragma unroll
    for (int rnd = 0; rnd < 4; ++rnd) {
      float4 r[4];
#pragma unroll
      for (int i = 0; i < 4; ++i) r[i] = src[rnd * 1024 + i * 256 + tid];
#pragma unroll
      for (int i = 0; i < 4; ++i) {
        ushort4 o;
        o.x = f2bf(r[i].x); o.y = f2bf(r[i].y);
        o.z = f2bf(r[i].z); o.w = f2bf(r[i].w);
        dst[rnd * 1024 + i * 256 + tid] = o;
      }
    }
  }
}

extern "C" void kernel_launch(void* const* d_in, const int* in_sizes, int n_in,
                              void* d_out, int out_size, void* d_ws, size_t ws_size,
                              hipStream_t stream) {
  const float* q    = (const float*)d_in[0];
  const float* k    = (const float*)d_in[1];
  // d_in[2] = v — unused by the reference output
  const float* fc_w = (const float*)d_in[3];
  const float* fc_b = (const float*)d_in[4];
  float* out = (float*)d_out;

  char* ws = (char*)d_ws;
  if (ws_size < 58720256) return;  // need 56 MB scratch
  u16* Qb  = (u16*)(ws);             // [4][1024][1024]   8.4 MB
  u16* Kt  = (u16*)(ws + 8388608);   // [16][256][1024]   8.4 MB
  u16* Wt  = (u16*)(ws + 16777216);  // [16][1024][1024] 33.6 MB
  u16* T2t = (u16*)(ws + 50331648);  // [4][1024][1024]   8.4 MB

  prep<<<3072, 256, 0, stream>>>(k, fc_w, Kt, Wt);
  gemm_bt<2, 1><<<dim3(16, 16), 256, 0, stream>>>(Wt, Kt, T2t, nullptr, nullptr, q, Qb);
  gemm_bt<8, 2><<<dim3(64, 4), 256, 0, stream>>>(Qb, T2t, nullptr, out, fc_b, nullptr, nullptr);
}